// Round 5
// baseline (478.723 us; speedup 1.0000x reference)
//
#include <hip/hip_runtime.h>

#define TPB 256
#define N_RELS 64
#define EPT 8   // edges per thread

typedef float f4 __attribute__((ext_vector_type(4)));
typedef int   i4 __attribute__((ext_vector_type(4)));

// sMB layout: [N_RELS][12] floats, 48B per rel (16B-aligned):
//  [0..8] = M[r] row-major, [9..11] = beta[r]
__device__ __forceinline__ void edge_compute(
    const float* __restrict__ sMB, int r,
    float p0, float p1, float p2,
    float c0, float c1, float c2,
    float zeps, float sf, float* __restrict__ o)
{
    const f4* mb = (const f4*)(sMB + r * 12);
    f4 q0 = mb[0], q1 = mb[1], q2 = mb[2];   // 3x ds_read_b128

    // scores = M[r] @ c
    float s0 = q0.x * c0 + q0.y * c1 + q0.z * c2;
    float s1 = q0.w * c0 + q1.x * c1 + q1.y * c2;
    float s2 = q1.z * c0 + q1.w * c1 + q2.x * c2;

    // softmax (max-subtracted)
    float mx = fmaxf(fmaxf(s0, s1), s2);
    float e0 = __expf(s0 - mx);
    float e1 = __expf(s1 - mx);
    float e2 = __expf(s2 - mx);
    float inv = __fdividef(1.0f, e0 + e1 + e2);
    float ch0 = e0 * inv, ch1 = e1 * inv, ch2 = e2 * inv;

    // alpha = p + b*(ch-p)
    float a0 = p0 + q2.y * (ch0 - p0);
    float a1 = p1 + q2.z * (ch1 - p1);
    float a2 = p2 + q2.w * (ch2 - p2);

    // entropy of clipped renormalized blend
    float z0 = fmaxf(zeps, p0 + ch0);
    float z1 = fmaxf(zeps, p1 + ch1);
    float z2 = fmaxf(zeps, p2 + ch2);
    float zinv = __fdividef(1.0f, z0 + z1 + z2);
    float zn0 = z0 * zinv, zn1 = z1 * zinv, zn2 = z2 * zinv;
    float ent = -(zn0 * __logf(zn0) + zn1 * __logf(zn1) + zn2 * __logf(zn2));

    // cosine similarity
    float dot = p0 * ch0 + p1 * ch1 + p2 * ch2;
    float np2 = p0 * p0 + p1 * p1 + p2 * p2;
    float nc2 = ch0 * ch0 + ch1 * ch1 + ch2 * ch2;
    float prod = np2 * nc2;
    float cosn = (prod > 0.0f) ? dot * rsqrtf(prod) : dot;  // norm==0 -> div by 1
    float cosv = 1.1f + cosn;

    float scale = sf * cosv * __fdividef(1.0f, ent);

    o[0] = a0 * scale;
    o[1] = a1 * scale;
    o[2] = a2 * scale;
}

__global__ __launch_bounds__(TPB, 4) void alpha_kernel(
    const float* __restrict__ prnt,
    const float* __restrict__ child,
    const int*   __restrict__ rels,
    const float* __restrict__ M,
    const float* __restrict__ beta,
    const float* __restrict__ zeps_p,
    const float* __restrict__ sf_p,
    float* __restrict__ out,
    int n_groups,   // full groups of EPT edges
    long n_edges)
{
    __shared__ float sMB[N_RELS * 12];
    for (int i = threadIdx.x; i < N_RELS * 12; i += TPB) {
        int r = i / 12, j = i - r * 12;
        sMB[i] = (j < 9) ? M[r * 9 + j] : beta[r * 3 + (j - 9)];
    }
    __syncthreads();

    const float zeps = *zeps_p;
    const float sf   = *sf_p;

    int g = blockIdx.x * TPB + threadIdx.x;

    if (g < n_groups) {
        const i4* r4 = (const i4*)rels  + (size_t)g * 2;
        const f4* p4 = (const f4*)prnt  + (size_t)g * 6;
        const f4* c4 = (const f4*)child + (size_t)g * 6;

        i4 R0 = r4[0], R1 = r4[1];   // issue rels first: feeds the LDS gather
        f4 P4[6], C4[6];
        #pragma unroll
        for (int i = 0; i < 6; ++i) P4[i] = __builtin_nontemporal_load(p4 + i);
        #pragma unroll
        for (int i = 0; i < 6; ++i) C4[i] = __builtin_nontemporal_load(c4 + i);

        int R[EPT] = {R0.x, R0.y, R0.z, R0.w, R1.x, R1.y, R1.z, R1.w};
        const float* P = (const float*)P4;   // 24 floats = 8 edges x 3
        const float* C = (const float*)C4;

        float O[EPT * 3];
        #pragma unroll
        for (int e = 0; e < EPT; ++e) {
            edge_compute(sMB, R[e],
                         P[3 * e], P[3 * e + 1], P[3 * e + 2],
                         C[3 * e], C[3 * e + 1], C[3 * e + 2],
                         zeps, sf, &O[3 * e]);
        }

        f4* o4 = (f4*)out + (size_t)g * 6;
        const f4* Ov = (const f4*)O;
        #pragma unroll
        for (int i = 0; i < 6; ++i) __builtin_nontemporal_store(Ov[i], o4 + i);
    } else {
        // scalar tail (n_edges % EPT != 0 only)
        long t = (long)g - n_groups;
        long eidx = (long)n_groups * EPT + t;
        if (t >= 0 && eidx < n_edges) {
            float o[3];
            edge_compute(sMB, rels[eidx],
                         prnt[eidx * 3 + 0], prnt[eidx * 3 + 1], prnt[eidx * 3 + 2],
                         child[eidx * 3 + 0], child[eidx * 3 + 1], child[eidx * 3 + 2],
                         zeps, sf, o);
            out[eidx * 3 + 0] = o[0];
            out[eidx * 3 + 1] = o[1];
            out[eidx * 3 + 2] = o[2];
        }
    }
}

extern "C" void kernel_launch(void* const* d_in, const int* in_sizes, int n_in,
                              void* d_out, int out_size, void* d_ws, size_t ws_size,
                              hipStream_t stream) {
    // input order: var_sfx, prnt_probs, child_probs, rels, M, beta, z_epsilon, scale_factor
    const float* prnt  = (const float*)d_in[1];
    const float* child = (const float*)d_in[2];
    const int*   rels  = (const int*)d_in[3];
    const float* M     = (const float*)d_in[4];
    const float* beta  = (const float*)d_in[5];
    const float* zeps  = (const float*)d_in[6];
    const float* sf    = (const float*)d_in[7];
    float* out = (float*)d_out;

    long n_edges  = in_sizes[3];            // rels is [E]
    int  n_groups = (int)(n_edges / EPT);   // full groups
    long tail     = n_edges - (long)n_groups * EPT;
    long work     = n_groups + tail;        // tail threads appended after groups
    int  blocks   = (int)((work + TPB - 1) / TPB);

    alpha_kernel<<<blocks, TPB, 0, stream>>>(prnt, child, rels, M, beta,
                                             zeps, sf, out, n_groups, n_edges);
}

// Round 6
// 328.657 us; speedup vs baseline: 1.4566x; 1.4566x over previous
//
#include <hip/hip_runtime.h>

#define TPB 256
#define N_RELS 64
#define EPT 8   // edges per thread

typedef float f4 __attribute__((ext_vector_type(4)));
typedef int   i4 __attribute__((ext_vector_type(4)));

// sMB layout: [N_RELS][12] floats, 48B per rel (16B-aligned):
//  [0..8] = M[r] row-major, [9..11] = beta[r]
__device__ __forceinline__ void edge_compute(
    const float* __restrict__ sMB, int r,
    float p0, float p1, float p2,
    float c0, float c1, float c2,
    float zeps, float sf, float* __restrict__ o)
{
    const f4* mb = (const f4*)(sMB + r * 12);
    f4 q0 = mb[0], q1 = mb[1], q2 = mb[2];   // 3x ds_read_b128

    // scores = M[r] @ c
    float s0 = q0.x * c0 + q0.y * c1 + q0.z * c2;
    float s1 = q0.w * c0 + q1.x * c1 + q1.y * c2;
    float s2 = q1.z * c0 + q1.w * c1 + q2.x * c2;

    // softmax (max-subtracted)
    float mx = fmaxf(fmaxf(s0, s1), s2);
    float e0 = __expf(s0 - mx);
    float e1 = __expf(s1 - mx);
    float e2 = __expf(s2 - mx);
    float inv = __fdividef(1.0f, e0 + e1 + e2);
    float ch0 = e0 * inv, ch1 = e1 * inv, ch2 = e2 * inv;

    // alpha = p + b*(ch-p)
    float a0 = p0 + q2.y * (ch0 - p0);
    float a1 = p1 + q2.z * (ch1 - p1);
    float a2 = p2 + q2.w * (ch2 - p2);

    // entropy of clipped renormalized blend
    float z0 = fmaxf(zeps, p0 + ch0);
    float z1 = fmaxf(zeps, p1 + ch1);
    float z2 = fmaxf(zeps, p2 + ch2);
    float zinv = __fdividef(1.0f, z0 + z1 + z2);
    float zn0 = z0 * zinv, zn1 = z1 * zinv, zn2 = z2 * zinv;
    float ent = -(zn0 * __logf(zn0) + zn1 * __logf(zn1) + zn2 * __logf(zn2));

    // cosine similarity
    float dot = p0 * ch0 + p1 * ch1 + p2 * ch2;
    float np2 = p0 * p0 + p1 * p1 + p2 * p2;
    float nc2 = ch0 * ch0 + ch1 * ch1 + ch2 * ch2;
    float prod = np2 * nc2;
    float cosn = (prod > 0.0f) ? dot * rsqrtf(prod) : dot;  // norm==0 -> div by 1
    float cosv = 1.1f + cosn;

    float scale = sf * cosv * __fdividef(1.0f, ent);

    o[0] = a0 * scale;
    o[1] = a1 * scale;
    o[2] = a2 * scale;
}

__global__ __launch_bounds__(TPB) void alpha_kernel(
    const float* __restrict__ prnt,
    const float* __restrict__ child,
    const int*   __restrict__ rels,
    const float* __restrict__ M,
    const float* __restrict__ beta,
    const float* __restrict__ zeps_p,
    const float* __restrict__ sf_p,
    float* __restrict__ out,
    int n_groups,   // full groups of EPT edges
    long n_edges)
{
    __shared__ float sMB[N_RELS * 12];
    for (int i = threadIdx.x; i < N_RELS * 12; i += TPB) {
        int r = i / 12, j = i - r * 12;
        sMB[i] = (j < 9) ? M[r * 9 + j] : beta[r * 3 + (j - 9)];
    }
    __syncthreads();

    const float zeps = *zeps_p;
    const float sf   = *sf_p;

    int g = blockIdx.x * TPB + threadIdx.x;

    if (g < n_groups) {
        const i4* r4 = (const i4*)rels  + (size_t)g * 2;
        const f4* p4 = (const f4*)prnt  + (size_t)g * 6;
        const f4* c4 = (const f4*)child + (size_t)g * 6;

        // issue ALL global loads up front (14 in flight), plain cached loads
        i4 R0 = r4[0], R1 = r4[1];
        f4 P4[6], C4[6];
        #pragma unroll
        for (int i = 0; i < 6; ++i) P4[i] = p4[i];
        #pragma unroll
        for (int i = 0; i < 6; ++i) C4[i] = c4[i];

        int R[EPT] = {R0.x, R0.y, R0.z, R0.w, R1.x, R1.y, R1.z, R1.w};
        const float* P = (const float*)P4;   // 24 floats = 8 edges x 3
        const float* C = (const float*)C4;

        float O[EPT * 3];
        #pragma unroll
        for (int e = 0; e < EPT; ++e) {
            edge_compute(sMB, R[e],
                         P[3 * e], P[3 * e + 1], P[3 * e + 2],
                         C[3 * e], C[3 * e + 1], C[3 * e + 2],
                         zeps, sf, &O[3 * e]);
        }

        f4* o4 = (f4*)out + (size_t)g * 6;
        const f4* Ov = (const f4*)O;
        #pragma unroll
        for (int i = 0; i < 6; ++i) o4[i] = Ov[i];
    } else {
        // scalar tail (n_edges % EPT != 0 only)
        long t = (long)g - n_groups;
        long eidx = (long)n_groups * EPT + t;
        if (t >= 0 && eidx < n_edges) {
            float o[3];
            edge_compute(sMB, rels[eidx],
                         prnt[eidx * 3 + 0], prnt[eidx * 3 + 1], prnt[eidx * 3 + 2],
                         child[eidx * 3 + 0], child[eidx * 3 + 1], child[eidx * 3 + 2],
                         zeps, sf, o);
            out[eidx * 3 + 0] = o[0];
            out[eidx * 3 + 1] = o[1];
            out[eidx * 3 + 2] = o[2];
        }
    }
}

extern "C" void kernel_launch(void* const* d_in, const int* in_sizes, int n_in,
                              void* d_out, int out_size, void* d_ws, size_t ws_size,
                              hipStream_t stream) {
    // input order: var_sfx, prnt_probs, child_probs, rels, M, beta, z_epsilon, scale_factor
    const float* prnt  = (const float*)d_in[1];
    const float* child = (const float*)d_in[2];
    const int*   rels  = (const int*)d_in[3];
    const float* M     = (const float*)d_in[4];
    const float* beta  = (const float*)d_in[5];
    const float* zeps  = (const float*)d_in[6];
    const float* sf    = (const float*)d_in[7];
    float* out = (float*)d_out;

    long n_edges  = in_sizes[3];            // rels is [E]
    int  n_groups = (int)(n_edges / EPT);   // full groups
    long tail     = n_edges - (long)n_groups * EPT;
    long work     = n_groups + tail;        // tail threads appended after groups
    int  blocks   = (int)((work + TPB - 1) / TPB);

    alpha_kernel<<<blocks, TPB, 0, stream>>>(prnt, child, rels, M, beta,
                                             zeps, sf, out, n_groups, n_edges);
}